// Round 9
// baseline (316.875 us; speedup 1.0000x reference)
//
#include <hip/hip_runtime.h>
#include <math.h>

#define LEN   2048
#define EDIM  512
#define NB    16
#define NH    8
#define HD    64
#define TOPK  7
#define NXCD  8
#define LBLK  64     // l's per topk block (single-wave blocks)

__device__ inline float2 cmul(float2 a, float2 b) {
    return make_float2(a.x * b.x - a.y * b.y, a.x * b.y + a.y * b.x);
}
__device__ inline float2 cadd(float2 a, float2 b) { return make_float2(a.x + b.x, a.y + b.y); }
__device__ inline float2 csub(float2 a, float2 b) { return make_float2(a.x - b.x, a.y - b.y); }
// XOR swizzle: arrays stay exactly 2048 float2 (A+Bs = 32 KB -> 5 blocks/CU),
// near-floor bank behavior for all pass strides (128 / 8 / 1 verified by hand).
__device__ inline int sw(int i) { return i ^ ((i >> 5) & 15); }

// e^{i*2pi*r} via HW trig (v_sin/cos take revolutions; dyadic args -> exact).
__device__ inline float2 cexp_rev(float r) {
    return make_float2(__builtin_amdgcn_cosf(r), __builtin_amdgcn_sinf(r));
}

// ---------------- radix-16 butterflies (4x4 Cooley-Tukey in registers) ----
// Forward DIF: X_p = sum_r v_r w16^{pr} (w16 = e^{-2pi i/16}), store
// X_p * w1^p at base + stride*p.  w1 = e^{-2pi i q/M} (external twiddle).
__device__ inline void fwd16(float2* P, int base, int stride, float2 w1) {
    const float C1 = 0.9238795325112867f;   // cos(pi/8)
    const float S1 = 0.3826834323650898f;   // sin(pi/8)
    const float C2 = 0.7071067811865476f;
    float2 v[16];
    #pragma unroll
    for (int r = 0; r < 16; ++r) v[r] = P[sw(base + stride * r)];
    // layer 1 (in place): DFT4f over {v[j], v[j+4], v[j+8], v[j+12]}, j=0..3
    // result t[j + 4*pm] in v[j + 4*pm]
    #pragma unroll
    for (int j = 0; j < 4; ++j) {
        float2 s02 = cadd(v[j], v[j + 8]),  d02 = csub(v[j], v[j + 8]);
        float2 s13 = cadd(v[j + 4], v[j + 12]), d13 = csub(v[j + 4], v[j + 12]);
        v[j]      = cadd(s02, s13);
        v[j + 8]  = csub(s02, s13);
        v[j + 4]  = make_float2(d02.x + d13.y, d02.y - d13.x);   // d02 - i*d13
        v[j + 12] = make_float2(d02.x - d13.y, d02.y + d13.x);   // d02 + i*d13
    }
    // internal twiddles: v[j+4*pm] *= w16^{j*pm}
    v[5]  = cmul(v[5],  make_float2(C1, -S1));    // k=1
    v[6]  = cmul(v[6],  make_float2(C2, -C2));    // k=2
    v[7]  = cmul(v[7],  make_float2(S1, -C1));    // k=3
    v[9]  = cmul(v[9],  make_float2(C2, -C2));    // k=2
    v[10] = make_float2(v[10].y, -v[10].x);       // k=4: * -i
    v[11] = cmul(v[11], make_float2(-C2, -C2));   // k=6
    v[13] = cmul(v[13], make_float2(S1, -C1));    // k=3
    v[14] = cmul(v[14], make_float2(-C2, -C2));   // k=6
    v[15] = cmul(v[15], make_float2(-C1, S1));    // k=9
    // layer 2 + external twiddles + store: for each pm, DFT4f over j
    float2 w2  = cmul(w1, w1);
    float2 w4  = cmul(w2, w2);
    float2 w8  = cmul(w4, w4);
    float2 w12 = cmul(w8, w4);
    float2 wpm = make_float2(1.f, 0.f);
    #pragma unroll
    for (int pm = 0; pm < 4; ++pm) {
        float2 u0 = v[4 * pm], u1 = v[4 * pm + 1], u2 = v[4 * pm + 2], u3 = v[4 * pm + 3];
        float2 s  = cadd(u0, u2), d  = csub(u0, u2);
        float2 sp = cadd(u1, u3), dp = csub(u1, u3);
        float2 X0 = cadd(s, sp);
        float2 X2 = csub(s, sp);
        float2 X1 = make_float2(d.x + dp.y, d.y - dp.x);   // d - i*dp
        float2 X3 = make_float2(d.x - dp.y, d.y + dp.x);   // d + i*dp
        P[sw(base + pm * stride)]        = cmul(X0, wpm);
        P[sw(base + (pm + 4) * stride)]  = cmul(X1, cmul(wpm, w4));
        P[sw(base + (pm + 8) * stride)]  = cmul(X2, cmul(wpm, w8));
        P[sw(base + (pm + 12) * stride)] = cmul(X3, cmul(wpm, w12));
        wpm = cmul(wpm, w1);
    }
}

// Inverse DIT: u_p = y_p * w1^p (w1 = e^{+2pi i q/M}), x_r = sum_p u_p w16^{+pr},
// store x_r at base + stride*r.
__device__ inline void inv16(float2* P, int base, int stride, float2 w1) {
    const float C1 = 0.9238795325112867f;
    const float S1 = 0.3826834323650898f;
    const float C2 = 0.7071067811865476f;
    float2 w2  = cmul(w1, w1);
    float2 w4  = cmul(w2, w2);
    float2 w8  = cmul(w4, w4);
    float2 w12 = cmul(w8, w4);
    float2 v[16];
    float2 wpm = make_float2(1.f, 0.f);
    #pragma unroll
    for (int pm = 0; pm < 4; ++pm) {
        v[pm]      = cmul(P[sw(base + pm * stride)], wpm);
        v[pm + 4]  = cmul(P[sw(base + (pm + 4) * stride)], cmul(wpm, w4));
        v[pm + 8]  = cmul(P[sw(base + (pm + 8) * stride)], cmul(wpm, w8));
        v[pm + 12] = cmul(P[sw(base + (pm + 12) * stride)], cmul(wpm, w12));
        wpm = cmul(wpm, w1);
    }
    // layer 1 (in place): DFT4i (w4 = +i) over {v[j], v[j+4], v[j+8], v[j+12]}
    #pragma unroll
    for (int j = 0; j < 4; ++j) {
        float2 s02 = cadd(v[j], v[j + 8]),  d02 = csub(v[j], v[j + 8]);
        float2 s13 = cadd(v[j + 4], v[j + 12]), d13 = csub(v[j + 4], v[j + 12]);
        v[j]      = cadd(s02, s13);
        v[j + 8]  = csub(s02, s13);
        v[j + 4]  = make_float2(d02.x - d13.y, d02.y + d13.x);   // d02 + i*d13
        v[j + 12] = make_float2(d02.x + d13.y, d02.y - d13.x);   // d02 - i*d13
    }
    // internal twiddles conj: v[j+4*rm] *= w16^{+j*rm}
    v[5]  = cmul(v[5],  make_float2(C1, S1));
    v[6]  = cmul(v[6],  make_float2(C2, C2));
    v[7]  = cmul(v[7],  make_float2(S1, C1));
    v[9]  = cmul(v[9],  make_float2(C2, C2));
    v[10] = make_float2(-v[10].y, v[10].x);       // * +i
    v[11] = cmul(v[11], make_float2(-C2, C2));
    v[13] = cmul(v[13], make_float2(S1, C1));
    v[14] = cmul(v[14], make_float2(-C2, C2));
    v[15] = cmul(v[15], make_float2(-C1, -S1));
    // layer 2: DFT4i over j; outputs x[rm + 4*rd], store plain
    #pragma unroll
    for (int rm = 0; rm < 4; ++rm) {
        float2 u0 = v[4 * rm], u1 = v[4 * rm + 1], u2 = v[4 * rm + 2], u3 = v[4 * rm + 3];
        float2 s  = cadd(u0, u2), d  = csub(u0, u2);
        float2 sp = cadd(u1, u3), dp = csub(u1, u3);
        P[sw(base + rm * stride)]        = cadd(s, sp);
        P[sw(base + (rm + 8) * stride)]  = csub(s, sp);
        P[sw(base + (rm + 4) * stride)]  = make_float2(d.x - dp.y, d.y + dp.x);  // d + i*dp
        P[sw(base + (rm + 12) * stride)] = make_float2(d.x + dp.y, d.y - dp.x);  // d - i*dp
    }
}

// ---------------- radix-8 final/first pass (M=8, no twiddles) ----------------
__device__ inline void fwd8nt(float2* P, int base) {
    const float C = 0.70710678118654752f;
    float2 v[8];
    #pragma unroll
    for (int r = 0; r < 8; ++r) v[r] = P[sw(base + r)];
    float2 y0 = cadd(v[0], v[4]), y1 = cadd(v[1], v[5]);
    float2 y2 = cadd(v[2], v[6]), y3 = cadd(v[3], v[7]);
    float2 t0 = csub(v[0], v[4]), t1 = csub(v[1], v[5]);
    float2 t2 = csub(v[2], v[6]), t3 = csub(v[3], v[7]);
    float2 z0 = t0;
    float2 z1 = make_float2(C * (t1.x + t1.y), C * (t1.y - t1.x));
    float2 z2 = make_float2(t2.y, -t2.x);
    float2 z3 = make_float2(C * (t3.y - t3.x), -C * (t3.x + t3.y));
    float2 a0 = cadd(y0, y2), a1 = cadd(y1, y3);
    float2 b0 = csub(y0, y2), tb = csub(y1, y3);
    float2 b1 = make_float2(tb.y, -tb.x);
    float2 c0 = cadd(z0, z2), c1 = cadd(z1, z3);
    float2 d0 = csub(z0, z2), td = csub(z1, z3);
    float2 d1 = make_float2(td.y, -td.x);
    P[sw(base)]     = cadd(a0, a1);
    P[sw(base + 4)] = csub(a0, a1);
    P[sw(base + 2)] = cadd(b0, b1);
    P[sw(base + 6)] = csub(b0, b1);
    P[sw(base + 1)] = cadd(c0, c1);
    P[sw(base + 5)] = csub(c0, c1);
    P[sw(base + 3)] = cadd(d0, d1);
    P[sw(base + 7)] = csub(d0, d1);
}

__device__ inline void inv8nt(float2* P, int base) {
    const float C = 0.70710678118654752f;
    float2 v[8];
    #pragma unroll
    for (int p = 0; p < 8; ++p) v[p] = P[sw(base + p)];
    float2 y0 = cadd(v[0], v[4]), y1 = cadd(v[1], v[5]);
    float2 y2 = cadd(v[2], v[6]), y3 = cadd(v[3], v[7]);
    float2 t0 = csub(v[0], v[4]), t1 = csub(v[1], v[5]);
    float2 t2 = csub(v[2], v[6]), t3 = csub(v[3], v[7]);
    float2 z0 = t0;
    float2 z1 = make_float2(C * (t1.x - t1.y), C * (t1.x + t1.y));
    float2 z2 = make_float2(-t2.y, t2.x);
    float2 z3 = make_float2(-C * (t3.x + t3.y), C * (t3.x - t3.y));
    float2 a0 = cadd(y0, y2), a1 = cadd(y1, y3);
    float2 b0 = csub(y0, y2), tb = csub(y1, y3);
    float2 b1 = make_float2(-tb.y, tb.x);
    float2 c0 = cadd(z0, z2), c1 = cadd(z1, z3);
    float2 d0 = csub(z0, z2), td = csub(z1, z3);
    float2 d1 = make_float2(-td.y, td.x);
    P[sw(base)]     = cadd(a0, a1);
    P[sw(base + 4)] = csub(a0, a1);
    P[sw(base + 2)] = cadd(b0, b1);
    P[sw(base + 6)] = csub(b0, b1);
    P[sw(base + 1)] = cadd(c0, c1);
    P[sw(base + 5)] = csub(c0, c1);
    P[sw(base + 3)] = cadd(d0, d1);
    P[sw(base + 7)] = csub(d0, d1);
}

// Storage slot of frequency k after DIF radices 16(128), 16(8), 8(1):
// slot = d0*128 + d1*8 + d2, d0 = k mod 16, d1 = (k>>4) mod 16, d2 = k>>8.
__device__ inline int slotF(int k) {
    return ((k & 15) << 7) | (((k >> 4) & 15) << 3) | ((k >> 8) & 7);
}

// Packed FFT correlation core, radix 16-16-8: 3 passes/direction (was 4).
// Forward: threads 0-127 own A, threads 128-255 own Bs (wave-uniform split).
// Inverse (A only): radix-8 pass uses all 256 threads; the two radix-16
// passes use threads 0-127 (waves 2-3 wait at the barrier).
__device__ inline void fft_core(float2* A, float2* Bs, int tid) {
    float2* P = (tid < 128) ? A : Bs;
    int tt = tid & 127;

    // F1: M=2048, R=16, stride 128, group q = tt
    fwd16(P, tt, 128, cexp_rev(-(float)tt * (1.0f / 2048.0f)));
    __syncthreads();
    // F2: M=128, R=16, stride 8, sub-block tt>>3, group q = tt&7
    fwd16(P, ((tt >> 3) << 7) + (tt & 7), 8, cexp_rev(-(float)(tt & 7) * (1.0f / 128.0f)));
    __syncthreads();
    // F3: M=8, R=8, stride 1, two groups per thread
    fwd8nt(P, tt << 4);
    fwd8nt(P, (tt << 4) + 8);
    __syncthreads();

    // Pointwise in digit-reversed (slotF) domain: Hermitian unpack of packed
    // real pair, C = Q*conj(K) per channel, repack W = C0 + i*C1.
    for (int f = tid; f <= 1024; f += 256) {
        int nf = (2048 - f) & 2047;
        int ia = sw(slotF(f));
        int ib = sw(slotF(nf));
        float2 z1 = A[ia],  z1n = A[ib];
        float2 z2 = Bs[ia], z2n = Bs[ib];
        float Qx = 0.5f * (z1.x + z1n.x), Qy = 0.5f * (z1.y - z1n.y);
        float Kx = 0.5f * (z1.y + z1n.y), Ky = 0.5f * (z1n.x - z1.x);
        float C1x = Qx * Kx + Qy * Ky;
        float C1y = Qy * Kx - Qx * Ky;
        float Px = 0.5f * (z2.x + z2n.x), Py = 0.5f * (z2.y - z2n.y);
        float Lx = 0.5f * (z2.y + z2n.y), Ly = 0.5f * (z2n.x - z2.x);
        float C2x = Px * Lx + Py * Ly;
        float C2y = Py * Lx - Px * Ly;
        A[ia] = make_float2(C1x - C2y, C1y + C2x);
        if (f != 0 && f != 1024)
            A[ib] = make_float2(C1x + C2y, C2x - C1y);
    }
    __syncthreads();

    // I1: M=8, R=8, stride 1 — all 256 threads, one group each
    inv8nt(A, tid << 3);
    __syncthreads();
    // I2: M=128, R=16, stride 8 — threads 0-127
    if (tid < 128)
        inv16(A, ((tid >> 3) << 7) + (tid & 7), 8, cexp_rev((float)(tid & 7) * (1.0f / 128.0f)));
    __syncthreads();
    // I3: M=2048, R=16, stride 128 — threads 0-127
    if (tid < 128)
        inv16(A, tid, 128, cexp_rev((float)tid * (1.0f / 2048.0f)));
    __syncthreads();
}

// K1: read q,k strided directly from (B,L,E); XCD-aware swizzle (round-5 win:
// FETCH 765->66 MB) keeps the 8 blocks sharing each 64B line on one XCD's L2.
__global__ __launch_bounds__(256) void fft_corr_strided(const float* __restrict__ q,
                                                        const float* __restrict__ k,
                                                        float* __restrict__ corr,
                                                        int chStart) {
    __shared__ float2 A[LEN];
    __shared__ float2 Bs[LEN];
    int bid = blockIdx.x;
    int nwg = gridDim.x;
    int cp  = ((nwg & (NXCD - 1)) == 0) ? (bid & (NXCD - 1)) * (nwg >> 3) + (bid >> 3)
                                        : bid;   // bijective only when nwg%8==0
    int chLocal = cp * 2;
    int gch = chStart + chLocal;
    int b   = gch >> 9;           // / EDIM
    int e   = gch & (EDIM - 1);   // even (channels paired)
    int tid = threadIdx.x;
    const float* qr = q + (size_t)b * LEN * EDIM + e;
    const float* kr = k + (size_t)b * LEN * EDIM + e;
    #pragma unroll
    for (int j = 0; j < LEN / 256; ++j) {
        int t = tid + 256 * j;
        float2 qv = *(const float2*)(qr + (size_t)t * EDIM);
        float2 kv = *(const float2*)(kr + (size_t)t * EDIM);
        A[sw(t)]  = make_float2(qv.x, kv.x);
        Bs[sw(t)] = make_float2(qv.y, kv.y);
    }
    __syncthreads();
    fft_core(A, Bs, tid);
    const float inv = 1.0f / (float)LEN;
    float4* c0 = (float4*)(corr + (size_t)chLocal * LEN);
    float4* c1 = (float4*)(corr + (size_t)(chLocal + 1) * LEN);
    for (int t4 = tid; t4 < LEN / 4; t4 += 256) {
        int t = t4 * 4;
        float2 e0 = A[sw(t)], e1 = A[sw(t + 1)], e2 = A[sw(t + 2)], e3 = A[sw(t + 3)];
        c0[t4] = make_float4(e0.x * inv, e1.x * inv, e2.x * inv, e3.x * inv);
        c1[t4] = make_float4(e0.y * inv, e1.y * inv, e2.y * inv, e3.y * inv);
    }
}

// K2: per (b,h,l): top-7 over 64 channel-scores, softmax, gather-weighted sum.
// UNCHANGED from round 8 (single-wave blocks, 4096 blocks, high occupancy).
__global__ __launch_bounds__(64) void topk_agg(const float* __restrict__ corr,
                                               const float* __restrict__ values,
                                               float* __restrict__ out,
                                               int bhBase) {
    __shared__ float2 w_d[LBLK][TOPK];   // (weight, bitcast delay) per local l
    int l0 = blockIdx.x * LBLK;
    int lh = blockIdx.y;            // local head index within chunk
    int bh = bhBase + lh;
    int b  = bh >> 3;
    int h  = bh & 7;
    int tid = threadIdx.x;          // 0..63

    // ---- phase 1: per-thread top-7 over the 64 channels of row l = l0+tid
    const float* cb = corr + (size_t)lh * HD * LEN + l0 + tid;
    float wk[TOPK];
    int   dk[TOPK];
    #pragma unroll
    for (int t = 0; t < TOPK; ++t) { wk[t] = -INFINITY; dk[t] = 0; }
    #pragma unroll 16
    for (int c = 0; c < HD; ++c) {
        float nv = cb[(size_t)c * LEN];
        int   nd = c;
        #pragma unroll
        for (int t = 0; t < TOPK; ++t) {   // stable: strict > keeps low index first
            bool  m  = nv > wk[t];
            float tv = wk[t]; int td = dk[t];
            wk[t] = m ? nv : tv;
            dk[t] = m ? nd : td;
            nv    = m ? tv : nv;
            nd    = m ? td : nd;
        }
    }
    float mx = wk[0], sum = 0.f;
    float e[TOPK];
    #pragma unroll
    for (int t = 0; t < TOPK; ++t) { e[t] = expf(wk[t] - mx); sum += e[t]; }
    float invs = 1.f / sum;
    #pragma unroll
    for (int t = 0; t < TOPK; ++t)
        w_d[tid][t] = make_float2(e[t] * invs, __int_as_float(dk[t]));
    __syncthreads();   // single wave: near-free

    // ---- phase 2: gather. tid = channel; this wave covers all 64 l.
    const float* vb = values + (size_t)b * LEN * EDIM + h * HD + tid;
    float*       ob = out    + (size_t)b * LEN * EDIM + h * HD + tid;
    for (int i0 = 0; i0 < LBLK; i0 += 4) {
        float acc0 = 0.f, acc1 = 0.f, acc2 = 0.f, acc3 = 0.f;
        int lb = l0 + i0;
        #pragma unroll
        for (int t = 0; t < TOPK; ++t) {
            float2 wd0 = w_d[i0 + 0][t];
            float2 wd1 = w_d[i0 + 1][t];
            float2 wd2 = w_d[i0 + 2][t];
            float2 wd3 = w_d[i0 + 3][t];
            int i0x = (lb + 0 - __float_as_int(wd0.y)) & (LEN - 1);
            int i1x = (lb + 1 - __float_as_int(wd1.y)) & (LEN - 1);
            int i2x = (lb + 2 - __float_as_int(wd2.y)) & (LEN - 1);
            int i3x = (lb + 3 - __float_as_int(wd3.y)) & (LEN - 1);
            acc0 += wd0.x * vb[(size_t)i0x * EDIM];
            acc1 += wd1.x * vb[(size_t)i1x * EDIM];
            acc2 += wd2.x * vb[(size_t)i2x * EDIM];
            acc3 += wd3.x * vb[(size_t)i3x * EDIM];
        }
        ob[(size_t)(lb + 0) * EDIM] = acc0;
        ob[(size_t)(lb + 1) * EDIM] = acc1;
        ob[(size_t)(lb + 2) * EDIM] = acc2;
        ob[(size_t)(lb + 3) * EDIM] = acc3;
    }
}

extern "C" void kernel_launch(void* const* d_in, const int* in_sizes, int n_in,
                              void* d_out, int out_size, void* d_ws, size_t ws_size,
                              hipStream_t stream) {
    const float* q = (const float*)d_in[0];
    const float* k = (const float*)d_in[1];
    const float* v = (const float*)d_in[2];
    float* out = (float*)d_out;

    const size_t CORR_BYTES = (size_t)NB * EDIM * LEN * sizeof(float);  // 64 MB

    if (ws_size >= CORR_BYTES) {
        // Full pipeline, transpose-free: corr (64 MB) lives in ws.
        float* corr = (float*)d_ws;
        fft_corr_strided<<<dim3(NB * EDIM / 2), dim3(256), 0, stream>>>(q, k, corr, 0);
        topk_agg<<<dim3(LEN / LBLK, NB * NH), dim3(LBLK), 0, stream>>>(corr, v, out, 0);
    } else {
        // Chunk by heads; corr chunk lives in ws (512 KB per head).
        const size_t HEAD_BYTES = (size_t)HD * LEN * sizeof(float);
        int headsPer = (int)(ws_size / HEAD_BYTES);
        if (headsPer < 1) headsPer = 1;
        if (headsPer > NB * NH) headsPer = NB * NH;
        float* corr = (float*)d_ws;
        for (int hs = 0; hs < NB * NH; hs += headsPer) {
            int hc = NB * NH - hs < headsPer ? NB * NH - hs : headsPer;
            fft_corr_strided<<<dim3(hc * HD / 2), dim3(256), 0, stream>>>(q, k, corr, hs * HD);
            topk_agg<<<dim3(LEN / LBLK, hc), dim3(LBLK), 0, stream>>>(corr, v, out, hs);
        }
    }
}